// Round 10
// baseline (475.510 us; speedup 1.0000x reference)
//
#include <hip/hip_runtime.h>
#include <math.h>

#define N_STEPS 50
#define DT 0.02f

typedef __attribute__((ext_vector_type(8))) short    bf16x8;
typedef __attribute__((ext_vector_type(4))) float    f32x4;
typedef __attribute__((ext_vector_type(4))) unsigned u32x4;

// RNE float->bf16 (software, setup-time only)
__device__ inline unsigned f2bf(float f) {
    unsigned u = __builtin_bit_cast(unsigned, f);
    return ((u + 0x7FFFu + ((u >> 16) & 1u)) >> 16);
}
__device__ inline unsigned pk2(float lo, float hi) {
    return (f2bf(lo) & 0xFFFFu) | (f2bf(hi) << 16);
}
// fast per-step packed convert (1 instr)
__device__ inline unsigned cvtpk(float lo, float hi) {
    unsigned r;
    asm("v_cvt_pk_bf16_f32 %0, %1, %2" : "=v"(r) : "v"(lo), "v"(hi));
    return r;
}
__device__ inline bf16x8 mk8(unsigned a, unsigned b, unsigned cc, unsigned d) {
    u32x4 t; t.x = a; t.y = b; t.z = cc; t.w = d;
    return __builtin_bit_cast(bf16x8, t);
}

// Block = 128 threads = 2 waves = one path-pair group of 64 paths.
//   wave 0 (net=0): z-net for paths [base, base+64)
//   wave 1 (net=1): q-net for same paths
// MFMA 16x16x32 bf16 MLP, W1/W2 fragments resident in VGPRs.
//
// Round-10 change vs round 9: DS-pipe decongestion. Round 9's DS-op count
// (~126/wave-step; the w3t f32x4 read sat inside the t4 loop = 64 redundant
// ds_read_b128/step) saturated the per-CU LDS unit (~1200 cyc/wave-step x
// 16 waves/CU ~= the measured wall). Fixes, all bitwise-neutral:
//   - W3 table stored COMPONENT-major (w3c[4][64] floats) so the 4 r-values
//     a lane needs are one 16B ds_read_b128 (was 4 reads of f32x4).
//   - z-wave L2/L3 reordered mt-outer/t4-inner: 3 w3-reads per mt hoisted
//     above the t4 loop -> 12 reads/step (was 64). Per-accumulator p[t4]
//     order over (mt,r) is unchanged -> bitwise identical.
//   - q-wave stays t4-outer with one f32x4 read per (t4,mt) -> 16 reads.
__global__ __launch_bounds__(128, 2) void bsde_kernel(
    const float* __restrict__ y0v, const float* __restrict__ Y0v,
    const float* __restrict__ qW1, const float* __restrict__ qb1,
    const float* __restrict__ qW2, const float* __restrict__ qb2,
    const float* __restrict__ qW3, const float* __restrict__ qb3,
    const float* __restrict__ zW1, const float* __restrict__ zb1,
    const float* __restrict__ zW2, const float* __restrict__ zb2,
    const float* __restrict__ zW3, const float* __restrict__ zb3,
    const float* __restrict__ dW,
    float* __restrict__ out, int B)
{
    const int lane = threadIdx.x & 63;
    const int net  = threadIdx.x >> 6;        // 0 = z-net wave, 1 = q-net wave
    const int c    = lane & 15;               // path-col within a 16-tile
    const int g    = lane >> 4;               // lane group
    const int p    = blockIdx.x * 64 + lane;  // this lane's path

    __shared__ unsigned short ex[2][4096];    // per-wave 8KB h1 exchange tile
    __shared__ float qbuf[2][64];
    __shared__ __align__(16) float w3c[4][64]; // W3 component-major: [0..2]=z, [3]=q

    const float* W1 = net ? qW1 : zW1;
    const float* b1 = net ? qb1 : zb1;
    const float* W2 = net ? qW2 : zW2;
    const float* b2 = net ? qb2 : zb2;
    const float* W3 = net ? qW3 : zW3;
    const float* b3 = net ? qb3 : zb3;

    // ---------------- one-time W3 -> LDS table (component-major) ----------------
    if (net) {
        w3c[3][lane] = W3[lane];
    } else {
        w3c[0][lane] = W3[3 * lane + 0];
        w3c[1][lane] = W3[3 * lane + 1];
        w3c[2][lane] = W3[3 * lane + 2];
    }

    // ---------------- one-time weight fragment preload ----------------
    bf16x8 w1f[4];                            // A-frags, L1 (W1 rows 0..3 + b1)
#pragma unroll
    for (int mt = 0; mt < 4; ++mt) {
        const int h = 16 * mt + c;
        unsigned d0 = 0, d1 = 0, d2 = 0;
        if (g == 0) {
            d0 = pk2(W1[0 * 64 + h], W1[1 * 64 + h]);   // k0=t, k1=y0
            d1 = pk2(W1[2 * 64 + h], W1[3 * 64 + h]);   // k2=y1, k3=y2
            d2 = f2bf(b1[h]) & 0xFFFFu;                 // k4=1-const row
        }
        w1f[mt] = mk8(d0, d1, d2, 0);
    }

    bf16x8 w2f[4][2];                         // A-frags, L2 (W2 transposed)
#pragma unroll
    for (int mt = 0; mt < 4; ++mt)
#pragma unroll
    for (int kt = 0; kt < 2; ++kt) {
        const int h = 16 * mt + c;            // h2 output index (M)
        const int k0 = 32 * kt + 8 * g;       // h1 input index base (K)
        unsigned d0 = pk2(W2[(k0 + 0) * 64 + h], W2[(k0 + 1) * 64 + h]);
        unsigned d1 = pk2(W2[(k0 + 2) * 64 + h], W2[(k0 + 3) * 64 + h]);
        unsigned d2 = pk2(W2[(k0 + 4) * 64 + h], W2[(k0 + 5) * 64 + h]);
        unsigned d3 = pk2(W2[(k0 + 6) * 64 + h], W2[(k0 + 7) * 64 + h]);
        w2f[mt][kt] = mk8(d0, d1, d2, d3);
    }

    f32x4 b2v[4];                             // b2 in C-layout (acc init)
#pragma unroll
    for (int mt = 0; mt < 4; ++mt)
#pragma unroll
    for (int r = 0; r < 4; ++r)
        b2v[mt][r] = b2[16 * mt + 4 * g + r];

    __syncthreads();                          // w3c visible (and setup done)

    char* exn = (char*)&ex[net][0];
    const int sw = (c & 7) << 4;              // LDS XOR swizzle key
    const unsigned jp2c = (g == 0) ? 0x3F80u : 0u;   // bf16(1.0) in k=4 slot

    const float sqrt_dt = sqrtf(DT);
    float y0 = y0v[0], y1 = y0v[1], y2 = y0v[2];
    float Y  = Y0v[0];

    for (int n = 0; n < N_STEPS; ++n) {
        const float t  = (float)n * DT;
        const int   bu = n & 1;

        const size_t idx = ((size_t)n * (size_t)B + (size_t)p) * 3;
        const float dr0 = dW[idx + 0];
        const float dr1 = dW[idx + 1];
        const float dr2 = dW[idx + 2];

        // ---- L1: per-t4 build B1 frag, 4 MFMA, relu+pack+swizzled write ----
#pragma unroll
        for (int t4 = 0; t4 < 4; ++t4) {
            const int src = 16 * t4 + c;
            const float s0 = __shfl(y0, src, 64);
            const float s1 = __shfl(y1, src, 64);
            const float s2 = __shfl(y2, src, 64);
            const unsigned a = cvtpk(t,  s0);
            const unsigned b = cvtpk(s1, s2);
            const bf16x8 xf = mk8((g == 0) ? a : 0u, (g == 0) ? b : 0u, jp2c, 0u);
#pragma unroll
            for (int mt = 0; mt < 4; ++mt) {
                f32x4 c1 = __builtin_amdgcn_mfma_f32_16x16x32_bf16(
                    w1f[mt], xf, (f32x4){0.f, 0.f, 0.f, 0.f}, 0, 0, 0);
                const unsigned lo = cvtpk(fmaxf(c1[0], 0.f), fmaxf(c1[1], 0.f));
                const unsigned hi = cvtpk(fmaxf(c1[2], 0.f), fmaxf(c1[3], 0.f));
                const int off = (((16 * t4 + c) * 128) + 32 * mt + 8 * g) ^ sw;
                *(unsigned long long*)(exn + off) =
                    ((unsigned long long)hi << 32) | (unsigned long long)lo;
            }
        }

        // ---- L2 + L3 partials ----
        float p0[4] = {0.f, 0.f, 0.f, 0.f};
        float p1[4] = {0.f, 0.f, 0.f, 0.f};
        float p2[4] = {0.f, 0.f, 0.f, 0.f};
        if (net == 0) {
            // z-wave: mt-outer so the 3 w3 reads hoist above the t4 loop.
            // p[t4] accumulation order over (mt,r) identical to t4-outer.
#pragma unroll
            for (int mt = 0; mt < 4; ++mt) {
                const int hb = 16 * mt + 4 * g;
                const f32x4 wz0 = *(const f32x4*)&w3c[0][hb];
                const f32x4 wz1 = *(const f32x4*)&w3c[1][hb];
                const f32x4 wz2 = *(const f32x4*)&w3c[2][hb];
#pragma unroll
                for (int t4 = 0; t4 < 4; ++t4) {
                    const int rb = ((16 * t4 + c) * 128) + 16 * g;
                    const bf16x8 hf0 = *(const bf16x8*)(exn + ((rb +  0) ^ sw));
                    const bf16x8 hf1 = *(const bf16x8*)(exn + ((rb + 64) ^ sw));
                    f32x4 acc = __builtin_amdgcn_mfma_f32_16x16x32_bf16(
                        w2f[mt][0], hf0, b2v[mt], 0, 0, 0);
                    acc = __builtin_amdgcn_mfma_f32_16x16x32_bf16(
                        w2f[mt][1], hf1, acc, 0, 0, 0);
#pragma unroll
                    for (int r = 0; r < 4; ++r) {
                        const float h = fmaxf(acc[r], 0.f);
                        p0[t4] = fmaf(h, wz0[r], p0[t4]);
                        p1[t4] = fmaf(h, wz1[r], p1[t4]);
                        p2[t4] = fmaf(h, wz2[r], p2[t4]);
                    }
                }
            }
        } else {
            // q-wave: t4-outer (hf read once per t4), one w3 read per (t4,mt).
#pragma unroll
            for (int t4 = 0; t4 < 4; ++t4) {
                const int rb = ((16 * t4 + c) * 128) + 16 * g;
                const bf16x8 hf0 = *(const bf16x8*)(exn + ((rb +  0) ^ sw));
                const bf16x8 hf1 = *(const bf16x8*)(exn + ((rb + 64) ^ sw));
#pragma unroll
                for (int mt = 0; mt < 4; ++mt) {
                    f32x4 acc = __builtin_amdgcn_mfma_f32_16x16x32_bf16(
                        w2f[mt][0], hf0, b2v[mt], 0, 0, 0);
                    acc = __builtin_amdgcn_mfma_f32_16x16x32_bf16(
                        w2f[mt][1], hf1, acc, 0, 0, 0);
                    const f32x4 wq = *(const f32x4*)&w3c[3][16 * mt + 4 * g];
#pragma unroll
                    for (int r = 0; r < 4; ++r) {
                        const float h = fmaxf(acc[r], 0.f);
                        p0[t4] = fmaf(h, wq[r], p0[t4]);
                    }
                }
            }
        }

        // ---- cross-lane reduce: land each path's outputs on its lane ----
        float out0, oz1 = 0.f, oz2 = 0.f;
        {
            float r4[4];
#pragma unroll
            for (int t4 = 0; t4 < 4; ++t4) {
                float v = p0[t4];
                v += __shfl_xor(v, 16, 64);
                v += __shfl_xor(v, 32, 64);
                r4[t4] = v;
            }
            float pick = r4[0];
            pick = (g == 1) ? r4[1] : pick;
            pick = (g == 2) ? r4[2] : pick;
            pick = (g == 3) ? r4[3] : pick;
            out0 = pick + b3[0];
        }
        if (net == 0) {
            float r4[4];
#pragma unroll
            for (int t4 = 0; t4 < 4; ++t4) {
                float v = p1[t4];
                v += __shfl_xor(v, 16, 64);
                v += __shfl_xor(v, 32, 64);
                r4[t4] = v;
            }
            float pick = r4[0];
            pick = (g == 1) ? r4[1] : pick;
            pick = (g == 2) ? r4[2] : pick;
            pick = (g == 3) ? r4[3] : pick;
            oz1 = pick + b3[1];
#pragma unroll
            for (int t4 = 0; t4 < 4; ++t4) {
                float v = p2[t4];
                v += __shfl_xor(v, 16, 64);
                v += __shfl_xor(v, 32, 64);
                r4[t4] = v;
            }
            pick = r4[0];
            pick = (g == 1) ? r4[1] : pick;
            pick = (g == 2) ? r4[2] : pick;
            pick = (g == 3) ? r4[3] : pick;
            oz2 = pick + b3[2];
        }

        // ---- one-way q exchange (q-wave -> z-wave), 1 barrier/step ----
        if (net == 1) qbuf[bu][lane] = out0;
        __syncthreads();
        const float qq = net ? out0 : qbuf[bu][lane];

        // ---- SDE update (fp32, same expression order as rounds 0-9) ----
        const float dw0 = dr0 * sqrt_dt;
        const float dw1 = dr1 * sqrt_dt;
        const float dw2 = dr2 * sqrt_dt;

        if (net == 0) {
            const float f = 0.5f * qq * qq;
            Y = Y - f * DT + (out0 * dw0 + oz1 * dw1 + oz2 * dw2);
        }

        const float s0 = 0.2f + 0.1f * tanhf(y0);
        const float s1 = 0.2f + 0.1f * tanhf(y1);
        const float s2 = 0.2f + 0.1f * tanhf(y2);
        y0 = y0 + (qq - y0) * DT + s0 * dw0;
        y1 = y1 + (qq - y1) * DT + s1 * dw1;
        y2 = y2 + (qq - y2) * DT + s2 * dw2;
    }

    // Only the z-waves contribute; each path counted once.
    if (net == 0) {
        const float term = y0 * y0 + y1 * y1 + y2 * y2;
        const float d    = Y - term;
        float val = d * d;
#pragma unroll
        for (int off = 32; off > 0; off >>= 1)
            val += __shfl_down(val, off, 64);
        if (lane == 0)
            atomicAdd(out, val * (1.0f / (float)B));
    }
}

extern "C" void kernel_launch(void* const* d_in, const int* in_sizes, int n_in,
                              void* d_out, int out_size, void* d_ws, size_t ws_size,
                              hipStream_t stream) {
    const float* y0  = (const float*)d_in[0];
    const float* Y0  = (const float*)d_in[1];
    const float* qW1 = (const float*)d_in[2];
    const float* qb1 = (const float*)d_in[3];
    const float* qW2 = (const float*)d_in[4];
    const float* qb2 = (const float*)d_in[5];
    const float* qW3 = (const float*)d_in[6];
    const float* qb3 = (const float*)d_in[7];
    const float* zW1 = (const float*)d_in[8];
    const float* zb1 = (const float*)d_in[9];
    const float* zW2 = (const float*)d_in[10];
    const float* zb2 = (const float*)d_in[11];
    const float* zW3 = (const float*)d_in[12];
    const float* zb3 = (const float*)d_in[13];
    const float* dW  = (const float*)d_in[14];

    const int B = in_sizes[14] / (N_STEPS * 3);   // 131072
    float* out = (float*)d_out;

    hipMemsetAsync(out, 0, sizeof(float), stream);

    const int threads = 128;                       // 2 waves: z-net + q-net
    const int blocks  = B / 64;                    // 2048 blocks, 64 paths each
    bsde_kernel<<<blocks, threads, 0, stream>>>(
        y0, Y0, qW1, qb1, qW2, qb2, qW3, qb3,
        zW1, zb1, zW2, zb2, zW3, zb3, dW, out, B);
}

// Round 11
// 400.564 us; speedup vs baseline: 1.1871x; 1.1871x over previous
//
#include <hip/hip_runtime.h>
#include <math.h>

#define N_STEPS 50
#define DT 0.02f

typedef __attribute__((ext_vector_type(8))) short    bf16x8;
typedef __attribute__((ext_vector_type(4))) float    f32x4;
typedef __attribute__((ext_vector_type(4))) unsigned u32x4;

// RNE float->bf16 (software, setup-time only)
__device__ inline unsigned f2bf(float f) {
    unsigned u = __builtin_bit_cast(unsigned, f);
    return ((u + 0x7FFFu + ((u >> 16) & 1u)) >> 16);
}
__device__ inline unsigned pk2(float lo, float hi) {
    return (f2bf(lo) & 0xFFFFu) | (f2bf(hi) << 16);
}
// fast per-step packed convert (1 instr)
__device__ inline unsigned cvtpk(float lo, float hi) {
    unsigned r;
    asm("v_cvt_pk_bf16_f32 %0, %1, %2" : "=v"(r) : "v"(lo), "v"(hi));
    return r;
}
__device__ inline bf16x8 mk8(unsigned a, unsigned b, unsigned cc, unsigned d) {
    u32x4 t; t.x = a; t.y = b; t.z = cc; t.w = d;
    return __builtin_bit_cast(bf16x8, t);
}
// tanh(x) = 1 - 2/(2^(x*2*log2 e) + 1); v_exp_f32 + v_rcp_f32.
// Abs error ~1e-6; enters sigma scaled by 0.1 -> negligible vs 7.7e-3 budget.
// Saturates correctly at +/-1 for large |x|.
__device__ inline float fast_tanh(float x) {
    float e, r;
    asm("v_exp_f32 %0, %1" : "=v"(e) : "v"(x * 2.8853900817779268f));
    asm("v_rcp_f32 %0, %1" : "=v"(r) : "v"(e + 1.0f));
    return fmaf(-2.0f, r, 1.0f);
}

// sum pv[t4] over lane-groups (xor 16, 32), then select this lane's tile.
__device__ inline float red4(const float pv[4], int g) {
    float r4[4];
#pragma unroll
    for (int t4 = 0; t4 < 4; ++t4) {
        float v = pv[t4];
        v += __shfl_xor(v, 16, 64);
        v += __shfl_xor(v, 32, 64);
        r4[t4] = v;
    }
    float pick = r4[0];
    pick = (g == 1) ? r4[1] : pick;
    pick = (g == 2) ? r4[2] : pick;
    pick = (g == 3) ? r4[3] : pick;
    return pick;
}

// Block = 64 threads = ONE wave handling BOTH nets for 64 paths.
//
// Round-11 change vs round 10: rounds 9/10 showed neither VALU (48%), MFMA
// (17%), nor the DS pipe (round-10 null) is saturated -- half the wall is
// issue-idle from latency chains + the per-step z<->q barrier coupling
// (z-wave is ~1.4x heavier; q-wave idles at the rendezvous; dW/shfl/SDE
// duplicated per pair). Since round 7 all weights are VGPR-resident, the
// round-6 scalar-cache hazard of free-running waves is gone. So: merge the
// two nets into one wave. M-tiles 0-3 = z-net, 4-7 = q-net; shared xf;
// one 16 KB ex tile [path][net][h1]; q computed locally.
//   -> ZERO barriers, zero qbuf, no duplicated work, waves fully
//      independent (drift freely to cover each other's stalls).
// Weight regs: w1f 32 + w2f 64 + b2v 32 = 128 VGPR; launch_bounds(64,2)
// caps at 256 -> no spill (tripwire: WRITE_SIZE must stay ~64 KB).
// tanhf -> fast_tanh (exp+rcp).
// Per-output accumulation order (mt,r) preserved from rounds 7-10.
__global__ __launch_bounds__(64, 2) void bsde_kernel(
    const float* __restrict__ y0v, const float* __restrict__ Y0v,
    const float* __restrict__ qW1, const float* __restrict__ qb1,
    const float* __restrict__ qW2, const float* __restrict__ qb2,
    const float* __restrict__ qW3, const float* __restrict__ qb3,
    const float* __restrict__ zW1, const float* __restrict__ zb1,
    const float* __restrict__ zW2, const float* __restrict__ zb2,
    const float* __restrict__ zW3, const float* __restrict__ zb3,
    const float* __restrict__ dW,
    float* __restrict__ out, int B)
{
    const int lane = threadIdx.x;             // 0..63
    const int c    = lane & 15;               // path-col within a 16-tile
    const int g    = lane >> 4;               // lane group
    const int p    = blockIdx.x * 64 + lane;  // this lane's path

    __shared__ unsigned short ex[64 * 128];   // 16KB: [path][net*64 + h1] bf16
    __shared__ __align__(16) float w3c[4][64]; // comp-major W3: 0..2 = z, 3 = q

    // ---------------- one-time W3 -> LDS table ----------------
    w3c[0][lane] = zW3[3 * lane + 0];
    w3c[1][lane] = zW3[3 * lane + 1];
    w3c[2][lane] = zW3[3 * lane + 2];
    w3c[3][lane] = qW3[lane];

    // ---------------- one-time weight fragment preload ----------------
    // mt 0..3 = z-net, mt 4..7 = q-net; h = 16*(mt&3)+c within the net.
    bf16x8 w1f[8];
#pragma unroll
    for (int mt = 0; mt < 8; ++mt) {
        const float* W1 = (mt < 4) ? zW1 : qW1;
        const float* b1 = (mt < 4) ? zb1 : qb1;
        const int h = 16 * (mt & 3) + c;
        unsigned d0 = 0, d1 = 0, d2 = 0;
        if (g == 0) {
            d0 = pk2(W1[0 * 64 + h], W1[1 * 64 + h]);   // k0=t, k1=y0
            d1 = pk2(W1[2 * 64 + h], W1[3 * 64 + h]);   // k2=y1, k3=y2
            d2 = f2bf(b1[h]) & 0xFFFFu;                 // k4=1-const row
        }
        w1f[mt] = mk8(d0, d1, d2, 0);
    }

    bf16x8 w2f[8][2];
#pragma unroll
    for (int mt = 0; mt < 8; ++mt) {
        const float* W2 = (mt < 4) ? zW2 : qW2;
        const int h = 16 * (mt & 3) + c;
#pragma unroll
        for (int kt = 0; kt < 2; ++kt) {
            const int k0 = 32 * kt + 8 * g;
            w2f[mt][kt] = mk8(
                pk2(W2[(k0 + 0) * 64 + h], W2[(k0 + 1) * 64 + h]),
                pk2(W2[(k0 + 2) * 64 + h], W2[(k0 + 3) * 64 + h]),
                pk2(W2[(k0 + 4) * 64 + h], W2[(k0 + 5) * 64 + h]),
                pk2(W2[(k0 + 6) * 64 + h], W2[(k0 + 7) * 64 + h]));
        }
    }

    f32x4 b2v[8];
#pragma unroll
    for (int mt = 0; mt < 8; ++mt) {
        const float* b2 = (mt < 4) ? zb2 : qb2;
#pragma unroll
        for (int r = 0; r < 4; ++r)
            b2v[mt][r] = b2[16 * (mt & 3) + 4 * g + r];
    }

    const float zb3_0 = zb3[0], zb3_1 = zb3[1], zb3_2 = zb3[2];
    const float qb3_0 = qb3[0];

    __syncthreads();                          // single wave; near-free

    char* exn = (char*)ex;
    const int sw = (c & 7) << 4;              // LDS XOR swizzle key (bits 4-6)
    const unsigned jp2c = (g == 0) ? 0x3F80u : 0u;   // bf16(1.0) in k=4 slot

    const float sqrt_dt = sqrtf(DT);
    float y0 = y0v[0], y1 = y0v[1], y2 = y0v[2];
    float Y  = Y0v[0];

    for (int n = 0; n < N_STEPS; ++n) {
        const float t = (float)n * DT;

        const size_t idx = ((size_t)n * (size_t)B + (size_t)p) * 3;
        const float dr0 = dW[idx + 0];
        const float dr1 = dW[idx + 1];
        const float dr2 = dW[idx + 2];

        // ---- L1: shared xf per t4, 8 MFMA (both nets), relu+pack+write ----
#pragma unroll
        for (int t4 = 0; t4 < 4; ++t4) {
            const int src = 16 * t4 + c;
            const float s0 = __shfl(y0, src, 64);
            const float s1 = __shfl(y1, src, 64);
            const float s2 = __shfl(y2, src, 64);
            const unsigned a = cvtpk(t,  s0);
            const unsigned b = cvtpk(s1, s2);
            const bf16x8 xf = mk8((g == 0) ? a : 0u, (g == 0) ? b : 0u, jp2c, 0u);
#pragma unroll
            for (int mt = 0; mt < 8; ++mt) {
                f32x4 c1 = __builtin_amdgcn_mfma_f32_16x16x32_bf16(
                    w1f[mt], xf, (f32x4){0.f, 0.f, 0.f, 0.f}, 0, 0, 0);
                const unsigned lo = cvtpk(fmaxf(c1[0], 0.f), fmaxf(c1[1], 0.f));
                const unsigned hi = cvtpk(fmaxf(c1[2], 0.f), fmaxf(c1[3], 0.f));
                const int off = (((16 * t4 + c) * 256) + (mt >> 2) * 128
                                 + 32 * (mt & 3) + 8 * g) ^ sw;
                *(unsigned long long*)(exn + off) =
                    ((unsigned long long)hi << 32) | (unsigned long long)lo;
            }
        }

        // ---- L2 + L3 partials, mt-outer (w3 reads hoisted per mt) ----
        float pz0[4] = {0.f, 0.f, 0.f, 0.f};
        float pz1[4] = {0.f, 0.f, 0.f, 0.f};
        float pz2[4] = {0.f, 0.f, 0.f, 0.f};
        float pq [4] = {0.f, 0.f, 0.f, 0.f};
#pragma unroll
        for (int mt = 0; mt < 8; ++mt) {
            const int hb = 16 * (mt & 3) + 4 * g;
            f32x4 wz0, wz1, wz2, wq;
            if (mt < 4) {
                wz0 = *(const f32x4*)&w3c[0][hb];
                wz1 = *(const f32x4*)&w3c[1][hb];
                wz2 = *(const f32x4*)&w3c[2][hb];
            } else {
                wq  = *(const f32x4*)&w3c[3][hb];
            }
#pragma unroll
            for (int t4 = 0; t4 < 4; ++t4) {
                const int rb = ((16 * t4 + c) * 256) + (mt >> 2) * 128 + 16 * g;
                const bf16x8 hf0 = *(const bf16x8*)(exn + ((rb +  0) ^ sw));
                const bf16x8 hf1 = *(const bf16x8*)(exn + ((rb + 64) ^ sw));
                f32x4 acc = __builtin_amdgcn_mfma_f32_16x16x32_bf16(
                    w2f[mt][0], hf0, b2v[mt], 0, 0, 0);
                acc = __builtin_amdgcn_mfma_f32_16x16x32_bf16(
                    w2f[mt][1], hf1, acc, 0, 0, 0);
#pragma unroll
                for (int r = 0; r < 4; ++r) {
                    const float h = fmaxf(acc[r], 0.f);
                    if (mt < 4) {
                        pz0[t4] = fmaf(h, wz0[r], pz0[t4]);
                        pz1[t4] = fmaf(h, wz1[r], pz1[t4]);
                        pz2[t4] = fmaf(h, wz2[r], pz2[t4]);
                    } else {
                        pq[t4]  = fmaf(h, wq[r],  pq[t4]);
                    }
                }
            }
        }

        // ---- cross-lane reduce: land each path's 4 outputs on its lane ----
        const float oz0 = red4(pz0, g) + zb3_0;
        const float oz1 = red4(pz1, g) + zb3_1;
        const float oz2 = red4(pz2, g) + zb3_2;
        const float qq  = red4(pq,  g) + qb3_0;

        // ---- SDE update (same expression order as rounds 0-10) ----
        const float dw0 = dr0 * sqrt_dt;
        const float dw1 = dr1 * sqrt_dt;
        const float dw2 = dr2 * sqrt_dt;

        const float f = 0.5f * qq * qq;
        Y = Y - f * DT + (oz0 * dw0 + oz1 * dw1 + oz2 * dw2);

        const float s0 = 0.2f + 0.1f * fast_tanh(y0);
        const float s1 = 0.2f + 0.1f * fast_tanh(y1);
        const float s2 = 0.2f + 0.1f * fast_tanh(y2);
        y0 = y0 + (qq - y0) * DT + s0 * dw0;
        y1 = y1 + (qq - y1) * DT + s1 * dw1;
        y2 = y2 + (qq - y2) * DT + s2 * dw2;
    }

    const float term = y0 * y0 + y1 * y1 + y2 * y2;
    const float d    = Y - term;
    float val = d * d;
#pragma unroll
    for (int off = 32; off > 0; off >>= 1)
        val += __shfl_down(val, off, 64);
    if (lane == 0)
        atomicAdd(out, val * (1.0f / (float)B));
}

extern "C" void kernel_launch(void* const* d_in, const int* in_sizes, int n_in,
                              void* d_out, int out_size, void* d_ws, size_t ws_size,
                              hipStream_t stream) {
    const float* y0  = (const float*)d_in[0];
    const float* Y0  = (const float*)d_in[1];
    const float* qW1 = (const float*)d_in[2];
    const float* qb1 = (const float*)d_in[3];
    const float* qW2 = (const float*)d_in[4];
    const float* qb2 = (const float*)d_in[5];
    const float* qW3 = (const float*)d_in[6];
    const float* qb3 = (const float*)d_in[7];
    const float* zW1 = (const float*)d_in[8];
    const float* zb1 = (const float*)d_in[9];
    const float* zW2 = (const float*)d_in[10];
    const float* zb2 = (const float*)d_in[11];
    const float* zW3 = (const float*)d_in[12];
    const float* zb3 = (const float*)d_in[13];
    const float* dW  = (const float*)d_in[14];

    const int B = in_sizes[14] / (N_STEPS * 3);   // 131072
    float* out = (float*)d_out;

    hipMemsetAsync(out, 0, sizeof(float), stream);

    const int threads = 64;                        // 1 wave, both nets
    const int blocks  = B / 64;                    // 2048 independent waves
    bsde_kernel<<<blocks, threads, 0, stream>>>(
        y0, Y0, qW1, qb1, qW2, qb2, qW3, qb3,
        zW1, zb1, zW2, zb2, zW3, zb3, dW, out, B);
}